// Round 5
// baseline (4965.593 us; speedup 1.0000x reference)
//
#include <hip/hip_runtime.h>
#include <math.h>

#define B_ 8192
#define DIN_ 2048
#define H_ 1024
#define V_ 6
#define T_ 6

typedef short bf16x8 __attribute__((ext_vector_type(8)));
typedef float f32x4 __attribute__((ext_vector_type(4)));

__device__ __forceinline__ unsigned short f32_bf16(float f) {
    unsigned u = __float_as_uint(f);
    u += 0x7FFFu + ((u >> 16) & 1u);
    return (unsigned short)(u >> 16);
}
__device__ __forceinline__ float bf16_f32(unsigned short h) {
    return __uint_as_float(((unsigned)h) << 16);
}

// ---------------------------------------------------------------------------
// conv_w: full 2048x1024 f32 W -> fragment planes, NKB=256 (W_enc only).
// plane addr (halves) = ((n>>4)*NKB + kb)*128 + (n&15)*8 + k8
// ---------------------------------------------------------------------------
__global__ __launch_bounds__(256) void conv_w(const float* __restrict__ W,
        unsigned short* __restrict__ hi, unsigned short* __restrict__ lo)
{
    const int t = blockIdx.x * 256 + threadIdx.x;   // 256K
    const int n = t & 1023;
    const int kb = t >> 10;                          // 0..255
    unsigned hq[4], lq[4];
#pragma unroll
    for (int p = 0; p < 4; ++p) {
        const float v0 = W[(size_t)(kb * 8 + 2 * p) * 1024 + n];
        const float v1 = W[(size_t)(kb * 8 + 2 * p + 1) * 1024 + n];
        const unsigned short h0 = f32_bf16(v0), h1 = f32_bf16(v1);
        const unsigned short l0 = f32_bf16(v0 - bf16_f32(h0));
        const unsigned short l1 = f32_bf16(v1 - bf16_f32(h1));
        hq[p] = (unsigned)h0 | ((unsigned)h1 << 16);
        lq[p] = (unsigned)l0 | ((unsigned)l1 << 16);
    }
    const size_t c = ((size_t)(n >> 4) * 256 + kb) * 128 + (size_t)(n & 15) * 8;
    *(uint4*)(hi + c) = make_uint4(hq[0], hq[1], hq[2], hq[3]);
    *(uint4*)(lo + c) = make_uint4(lq[0], lq[1], lq[2], lq[3]);
}

// ---------------------------------------------------------------------------
// conv_wb: BOTTOM half (rows 1024..2047) of 2048x1024 W -> planes, NKB=128.
// ---------------------------------------------------------------------------
__global__ __launch_bounds__(256) void conv_wb(const float* __restrict__ W,
        unsigned short* __restrict__ hi, unsigned short* __restrict__ lo)
{
    const int t = blockIdx.x * 256 + threadIdx.x;   // 128K
    const int n = t & 1023;
    const int kb = t >> 10;                          // 0..127
    unsigned hq[4], lq[4];
#pragma unroll
    for (int p = 0; p < 4; ++p) {
        const float v0 = W[(size_t)(1024 + kb * 8 + 2 * p) * 1024 + n];
        const float v1 = W[(size_t)(1024 + kb * 8 + 2 * p + 1) * 1024 + n];
        const unsigned short h0 = f32_bf16(v0), h1 = f32_bf16(v1);
        const unsigned short l0 = f32_bf16(v0 - bf16_f32(h0));
        const unsigned short l1 = f32_bf16(v1 - bf16_f32(h1));
        hq[p] = (unsigned)h0 | ((unsigned)h1 << 16);
        lq[p] = (unsigned)l0 | ((unsigned)l1 << 16);
    }
    const size_t c = ((size_t)(n >> 4) * 128 + kb) * 128 + (size_t)(n & 15) * 8;
    *(uint4*)(hi + c) = make_uint4(hq[0], hq[1], hq[2], hq[3]);
    *(uint4*)(lo + c) = make_uint4(lq[0], lq[1], lq[2], lq[3]);
}

// ---------------------------------------------------------------------------
// conv_x: x (8192x2048 f32) -> A planes, NKB=256.
// ---------------------------------------------------------------------------
__global__ __launch_bounds__(256) void conv_x(const float* __restrict__ X,
        unsigned short* __restrict__ hi, unsigned short* __restrict__ lo)
{
    const size_t t = (size_t)blockIdx.x * 256 + threadIdx.x;  // 8192*256
    const int kb = (int)(t & 255);
    const int m = (int)(t >> 8);
    const float4 f0 = *(const float4*)(X + (size_t)m * 2048 + kb * 8);
    const float4 f1 = *(const float4*)(X + (size_t)m * 2048 + kb * 8 + 4);
    const float v[8] = {f0.x, f0.y, f0.z, f0.w, f1.x, f1.y, f1.z, f1.w};
    unsigned hq[4], lq[4];
#pragma unroll
    for (int p = 0; p < 4; ++p) {
        const unsigned short h0 = f32_bf16(v[2 * p]);
        const unsigned short h1 = f32_bf16(v[2 * p + 1]);
        const unsigned short l0 = f32_bf16(v[2 * p] - bf16_f32(h0));
        const unsigned short l1 = f32_bf16(v[2 * p + 1] - bf16_f32(h1));
        hq[p] = (unsigned)h0 | ((unsigned)h1 << 16);
        lq[p] = (unsigned)l0 | ((unsigned)l1 << 16);
    }
    const size_t c = ((size_t)(m >> 4) * 256 + kb) * 128 + (size_t)(m & 15) * 8;
    *(uint4*)(hi + c) = make_uint4(hq[0], hq[1], hq[2], hq[3]);
    *(uint4*)(lo + c) = make_uint4(lq[0], lq[1], lq[2], lq[3]);
}

// ---------------------------------------------------------------------------
// prep_tables: P_m[tok][n] = sum_k emb[tok][k] * W_m[k][n] + b_m[n]
// ---------------------------------------------------------------------------
__global__ __launch_bounds__(256) void prep_tables(
        const float* __restrict__ Wz, const float* __restrict__ Wr,
        const float* __restrict__ Wh,
        const float* __restrict__ bz, const float* __restrict__ br,
        const float* __restrict__ bh,
        const float* __restrict__ Wt, const float* __restrict__ bt,
        const float* __restrict__ se,
        float* __restrict__ Pz, float* __restrict__ Pr, float* __restrict__ Ph)
{
    __shared__ float emb[7][1024];
    const int tid = threadIdx.x;
    for (int i = tid; i < 7 * 1024; i += 256) {
        const int r = i >> 10, k = i & 1023;
        emb[r][k] = (r < 6) ? (Wt[(size_t)r * 1024 + k] + bt[k]) : se[k];
    }
    __syncthreads();
    const float* W = (blockIdx.y == 0) ? Wz : ((blockIdx.y == 1) ? Wr : Wh);
    const float* bb = (blockIdx.y == 0) ? bz : ((blockIdx.y == 1) ? br : bh);
    float* P = (blockIdx.y == 0) ? Pz : ((blockIdx.y == 1) ? Pr : Ph);
    const int n = blockIdx.x * 256 + tid;
    float acc[7] = {0.f, 0.f, 0.f, 0.f, 0.f, 0.f, 0.f};
    for (int k = 0; k < 1024; ++k) {
        const float wv = W[(size_t)k * 1024 + n];
#pragma unroll
        for (int r = 0; r < 7; ++r) acc[r] = fmaf(emb[r][k], wv, acc[r]);
    }
    const float bvv = bb[n];
#pragma unroll
    for (int r = 0; r < 7; ++r) P[(size_t)r * 1024 + n] = acc[r] + bvv;
}

// ---------------------------------------------------------------------------
// init_misc: tokidx = 6 (start), rc = 1, nt = 0.
// ---------------------------------------------------------------------------
__global__ __launch_bounds__(256) void init_misc(
        int* __restrict__ tokidx, float* __restrict__ rc, float* __restrict__ nt)
{
    const int t = blockIdx.x * 256 + threadIdx.x;   // 8192
    tokidx[t] = 6;
    rc[t] = 1.0f;
    nt[t] = 0.0f;
}

// ---------------------------------------------------------------------------
// gemm_bt: 128x256 macro-tile (two 128x128 halves sharing A), BK=32,
// split-bf16 3-pass MFMA, register-prefetch software pipeline.
//   Per step: ds_write staged regs (vmcnt wait lands here, ~1 step after
//   issue -> latency hidden by MFMA), barrier, issue next step's 12 uint4
//   global loads, then 96 MFMA/wave.
//   mode 0: encoder (grid 4,64). halves = n-blocks 2bx,2bx+1 of W_enc.
//   mode 1: z/r (grid 8,64). half0 = Wz n-block bx -> z, half1 = Wr -> rh.
//   mode 2: h_tilde (grid 4,64). halves = n-blocks 2bx,2bx+1 of Wh; GRU update.
// ---------------------------------------------------------------------------
__global__ __launch_bounds__(256, 2)
void gemm_bt(
    const unsigned short* __restrict__ A_hi, const unsigned short* __restrict__ A_lo,
    const unsigned short* __restrict__ B0_hi, const unsigned short* __restrict__ B0_lo,
    const unsigned short* __restrict__ B1_hi, const unsigned short* __restrict__ B1_lo,
    const float* __restrict__ P0, const float* __restrict__ P1,
    const int* __restrict__ tokidx,
    const float* __restrict__ zbuf, float* __restrict__ hbuf,
    float* __restrict__ outf,
    unsigned short* __restrict__ ophi, unsigned short* __restrict__ oplo,
    int nkb, int mode)
{
    // 48KB: Ahi[0,4096) Alo[4096,8192) B0hi[8192,12288) B0lo[12288,16384)
    //       B1hi[16384,20480) B1lo[20480,24576)   (units: halves)
    __shared__ unsigned short lds[24576];

    const int tid = threadIdx.x;
    const int lane = tid & 63;
    const int w = tid >> 6;

    // XCD-aware swizzle (bijective relabel of NX x 64 grid)
    const int NX = gridDim.x;
    const int lin = blockIdx.y * NX + blockIdx.x;
    const int xcd = lin & 7;
    const int idx = lin >> 3;
    const int bx = idx % NX;
    const int by = xcd * 8 + idx / NX;

    int nblk0, nblk1;
    if (mode == 1) { nblk0 = bx; nblk1 = bx; }
    else           { nblk0 = 2 * bx; nblk1 = 2 * bx + 1; }

    const int m0 = by * 128;
    const int SD = nkb * 128;               // subtile delta (halves)

    // per-thread global base pointers (subtile 2w, step 0)
    const size_t aoff = ((size_t)(by * 8 + 2 * w) * nkb) * 128 + lane * 8;
    const unsigned short* pAh = A_hi + aoff;
    const unsigned short* pAl = A_lo + aoff;
    const size_t b0off = ((size_t)(nblk0 * 8 + 2 * w) * nkb) * 128 + lane * 8;
    const unsigned short* pB0h = B0_hi + b0off;
    const unsigned short* pB0l = B0_lo + b0off;
    const size_t b1off = ((size_t)(nblk1 * 8 + 2 * w) * nkb) * 128 + lane * 8;
    const unsigned short* pB1h = B1_hi + b1off;
    const unsigned short* pB1l = B1_lo + b1off;

    // LDS write destinations (wave w stages subtiles 2w, 2w+1 of 6 arrays)
    const int l0 = 2 * w * 512 + lane * 8;
    const int l1 = l0 + 512;

    f32x4 acc[4][8];
#pragma unroll
    for (int i = 0; i < 4; ++i)
#pragma unroll
        for (int j = 0; j < 8; ++j) acc[i][j] = (f32x4){0.f, 0.f, 0.f, 0.f};

    const int wr = w >> 1, wc = w & 1;
    const int fq = lane >> 4;
    const int fm = lane & 15;
    const int nsteps = nkb >> 2;

    // prefetch step 0
    uint4 rA0h = *(const uint4*)(pAh);
    uint4 rA1h = *(const uint4*)(pAh + SD);
    uint4 rA0l = *(const uint4*)(pAl);
    uint4 rA1l = *(const uint4*)(pAl + SD);
    uint4 rB00h = *(const uint4*)(pB0h);
    uint4 rB01h = *(const uint4*)(pB0h + SD);
    uint4 rB00l = *(const uint4*)(pB0l);
    uint4 rB01l = *(const uint4*)(pB0l + SD);
    uint4 rB10h = *(const uint4*)(pB1h);
    uint4 rB11h = *(const uint4*)(pB1h + SD);
    uint4 rB10l = *(const uint4*)(pB1l);
    uint4 rB11l = *(const uint4*)(pB1l + SD);

#pragma unroll 1
    for (int s = 0; s < nsteps; ++s) {
        __syncthreads();
        *(uint4*)(lds + l0)          = rA0h;
        *(uint4*)(lds + l1)          = rA1h;
        *(uint4*)(lds + 4096 + l0)   = rA0l;
        *(uint4*)(lds + 4096 + l1)   = rA1l;
        *(uint4*)(lds + 8192 + l0)   = rB00h;
        *(uint4*)(lds + 8192 + l1)   = rB01h;
        *(uint4*)(lds + 12288 + l0)  = rB00l;
        *(uint4*)(lds + 12288 + l1)  = rB01l;
        *(uint4*)(lds + 16384 + l0)  = rB10h;
        *(uint4*)(lds + 16384 + l1)  = rB11h;
        *(uint4*)(lds + 20480 + l0)  = rB10l;
        *(uint4*)(lds + 20480 + l1)  = rB11l;
        __syncthreads();

        if (s + 1 < nsteps) {
            const int so = (s + 1) * 512;
            rA0h  = *(const uint4*)(pAh + so);
            rA1h  = *(const uint4*)(pAh + SD + so);
            rA0l  = *(const uint4*)(pAl + so);
            rA1l  = *(const uint4*)(pAl + SD + so);
            rB00h = *(const uint4*)(pB0h + so);
            rB01h = *(const uint4*)(pB0h + SD + so);
            rB00l = *(const uint4*)(pB0l + so);
            rB01l = *(const uint4*)(pB0l + SD + so);
            rB10h = *(const uint4*)(pB1h + so);
            rB11h = *(const uint4*)(pB1h + SD + so);
            rB10l = *(const uint4*)(pB1l + so);
            rB11l = *(const uint4*)(pB1l + SD + so);
        }

        bf16x8 ah[4], al[4];
#pragma unroll
        for (int i = 0; i < 4; ++i) {
            const int ra = (wr * 4 + i) * 512 + fq * 128 + fm * 8;
            ah[i] = *(const bf16x8*)(lds + ra);
            al[i] = *(const bf16x8*)(lds + 4096 + ra);
        }
        const int bbase = 8192 + wc * 8192;
#pragma unroll
        for (int j = 0; j < 8; ++j) {
            const int rb = bbase + j * 512 + fq * 128 + fm * 8;
            const bf16x8 bh = *(const bf16x8*)(lds + rb);
            const bf16x8 bl = *(const bf16x8*)(lds + 4096 + rb);
#pragma unroll
            for (int i = 0; i < 4; ++i) {
                acc[i][j] = __builtin_amdgcn_mfma_f32_16x16x32_bf16(ah[i], bh, acc[i][j], 0, 0, 0);
                acc[i][j] = __builtin_amdgcn_mfma_f32_16x16x32_bf16(ah[i], bl, acc[i][j], 0, 0, 0);
                acc[i][j] = __builtin_amdgcn_mfma_f32_16x16x32_bf16(al[i], bh, acc[i][j], 0, 0, 0);
            }
        }
    }

    // ---- epilogue: wave (wr,wc) covers rows m0+wr*64+[0,64), cols of half wc ----
    const int colb = (mode == 1) ? bx * 128 : (2 * bx + wc) * 128;
    const float* Pm = (mode == 1 && wc == 1) ? P1 : P0;

#pragma unroll
    for (int i = 0; i < 4; ++i) {
        int toks[4];
#pragma unroll
        for (int r = 0; r < 4; ++r) {
            const int row = m0 + wr * 64 + i * 16 + fq * 4 + r;
            toks[r] = tokidx ? tokidx[row] : 0;
        }
#pragma unroll
        for (int j = 0; j < 8; ++j) {
            const int col = colb + j * 16 + fm;
#pragma unroll
            for (int r = 0; r < 4; ++r) {
                const int row = m0 + wr * 64 + i * 16 + fq * 4 + r;
                const float v = acc[i][j][r] + Pm[(size_t)toks[r] * 1024 + col];
                const size_t off = (size_t)row * 1024 + col;
                const size_t pc = ((size_t)(row >> 4) * 128 + (col >> 3)) * 128
                                  + (size_t)(row & 15) * 8 + (col & 7);
                if (mode == 0) {
                    hbuf[off] = v;
                    const unsigned short hv = f32_bf16(v);
                    ophi[pc] = hv;
                    oplo[pc] = f32_bf16(v - bf16_f32(hv));
                } else if (mode == 1) {
                    const float sg = 1.0f / (1.0f + expf(-v));
                    if (wc == 0) {
                        outf[off] = sg;            // z
                    } else {
                        const float rh = sg * hbuf[off];   // r*h
                        const unsigned short hv = f32_bf16(rh);
                        ophi[pc] = hv;
                        oplo[pc] = f32_bf16(rh - bf16_f32(hv));
                    }
                } else {
                    const float tv = tanhf(v);
                    const float zv = zbuf[off];
                    const float hn = (1.0f - zv) * hbuf[off] + zv * tv;
                    hbuf[off] = hn;
                    const unsigned short hv = f32_bf16(hn);
                    ophi[pc] = hv;
                    oplo[pc] = f32_bf16(hn - bf16_f32(hv));
                }
            }
        }
    }
}

// ---------------------------------------------------------------------------
// step_tok: one wave per batch row.
// ---------------------------------------------------------------------------
__global__ __launch_bounds__(256)
void step_tok(const float* __restrict__ h,
              const float* __restrict__ W_out, const float* __restrict__ b_out,
              const float* __restrict__ u,
              float* __restrict__ rc, float* __restrict__ nt,
              int* __restrict__ tokidx,
              float* __restrict__ out_msg, float* __restrict__ out_logits,
              float* __restrict__ out_nt, int t)
{
    const int lane = threadIdx.x & 63;
    const int wv = threadIdx.x >> 6;
    const int b = blockIdx.x * 4 + wv;

    const float* hr = h + (size_t)b * H_;
    float s[6] = {0.f, 0.f, 0.f, 0.f, 0.f, 0.f};
#pragma unroll
    for (int i = 0; i < 4; ++i) {
        const int k0 = i * 256 + lane * 4;
        const float4 hv = *(const float4*)(hr + k0);
        const float he[4] = {hv.x, hv.y, hv.z, hv.w};
#pragma unroll
        for (int e = 0; e < 4; ++e) {
            const float* wp = W_out + (size_t)(k0 + e) * V_;
            const float xv = he[e];
#pragma unroll
            for (int v = 0; v < 6; ++v) s[v] = fmaf(xv, wp[v], s[v]);
        }
    }
#pragma unroll
    for (int m = 1; m < 64; m <<= 1) {
#pragma unroll
        for (int v = 0; v < 6; ++v) s[v] += __shfl_xor(s[v], m, 64);
    }

    float lg[6];
#pragma unroll
    for (int v = 0; v < 6; ++v) lg[v] = s[v] + b_out[v];

    const float* ub = u + (size_t)b * V_;
    const float eps = 1e-10f;
    float aa[6];
#pragma unroll
    for (int v = 0; v < 6; ++v) {
        const float g = -logf(-logf(ub[v] + eps) + eps);
        aa[v] = lg[v] + g;  // TAU = 1
    }
    int tok = 0;
    float best = aa[0];
#pragma unroll
    for (int v = 1; v < 6; ++v)
        if (aa[v] > best) { best = aa[v]; tok = v; }

    if (lane == 0) {
        const float rco = rc[b];
#pragma unroll
        for (int v = 0; v < 6; ++v) out_logits[(size_t)b * 6 + v] = lg[v];
#pragma unroll
        for (int v = 0; v < 6; ++v)
            out_msg[(size_t)b * 36 + t * 6 + v] = (v == tok) ? rco : 0.0f;
        const float ntn = nt[b] + rco;
        nt[b] = ntn;
        out_nt[b] = ntn;
        rc[b] = (tok == 5) ? 0.0f : rco;
        tokidx[b] = tok;
    }
}

// ---------------------------------------------------------------------------
extern "C" void kernel_launch(void* const* d_in, const int* in_sizes, int n_in,
                              void* d_out, int out_size, void* d_ws, size_t ws_size,
                              hipStream_t stream)
{
    (void)in_sizes; (void)n_in; (void)out_size; (void)ws_size;
    const float* x       = (const float*)d_in[0];
    const float* u_noise = (const float*)d_in[1];
    const float* W_enc   = (const float*)d_in[2];
    const float* b_enc   = (const float*)d_in[3];
    const float* start_e = (const float*)d_in[4];
    const float* W_tok   = (const float*)d_in[5];
    const float* b_tok   = (const float*)d_in[6];
    const float* Wz      = (const float*)d_in[7];
    const float* bz      = (const float*)d_in[8];
    const float* Wr      = (const float*)d_in[9];
    const float* br      = (const float*)d_in[10];
    const float* Wh      = (const float*)d_in[11];
    const float* bh      = (const float*)d_in[12];
    const float* W_out   = (const float*)d_in[13];
    const float* b_out   = (const float*)d_in[14];

    float* out = (float*)d_out;
    float* out_msg = out;                                   // (B, T*V)
    float* out_logits = out + (size_t)B_ * T_ * V_;         // (T, B, V)
    float* out_nt = out_logits + (size_t)T_ * B_ * V_;      // (B,)

    // ---- workspace layout (~148.1 MB) ----
    char* wsb = (char*)d_ws;
    const size_t MB = 1024 * 1024;
    unsigned short* wzb_hi = (unsigned short*)(wsb + 0 * MB);    // 2MB each
    unsigned short* wzb_lo = (unsigned short*)(wsb + 2 * MB);
    unsigned short* wrb_hi = (unsigned short*)(wsb + 4 * MB);
    unsigned short* wrb_lo = (unsigned short*)(wsb + 6 * MB);
    unsigned short* whb_hi = (unsigned short*)(wsb + 8 * MB);
    unsigned short* whb_lo = (unsigned short*)(wsb + 10 * MB);
    unsigned short* we_hi  = (unsigned short*)(wsb + 12 * MB);   // 4MB
    unsigned short* we_lo  = (unsigned short*)(wsb + 16 * MB);   // 4MB
    unsigned short* x_hi   = (unsigned short*)(wsb + 20 * MB);   // 32MB
    unsigned short* x_lo   = (unsigned short*)(wsb + 52 * MB);   // 32MB
    float*  zbuf  = (float*)(wsb + 20 * MB);                     // alias x_hi
    unsigned short* rh_hi  = (unsigned short*)(wsb + 52 * MB);   // alias x_lo
    unsigned short* rh_lo  = (unsigned short*)(wsb + 68 * MB);
    float*  hbuf  = (float*)(wsb + 84 * MB);                     // 32MB
    unsigned short* h_hi   = (unsigned short*)(wsb + 116 * MB);  // 16MB
    unsigned short* h_lo   = (unsigned short*)(wsb + 132 * MB);  // 16MB
    float* Pz = (float*)(wsb + 148 * MB);                        // 7x1024 each
    float* Pr = Pz + 7 * 1024;
    float* Ph = Pr + 7 * 1024;
    int* tokidx = (int*)(Ph + 7 * 1024);
    float* rcb = (float*)(tokidx + B_);
    float* ntb = rcb + B_;

    // ---- one-time conversions / tables ----
    conv_wb<<<512, 256, 0, stream>>>(Wz, wzb_hi, wzb_lo);
    conv_wb<<<512, 256, 0, stream>>>(Wr, wrb_hi, wrb_lo);
    conv_wb<<<512, 256, 0, stream>>>(Wh, whb_hi, whb_lo);
    conv_w<<<1024, 256, 0, stream>>>(W_enc, we_hi, we_lo);
    conv_x<<<8192, 256, 0, stream>>>(x, x_hi, x_lo);
    prep_tables<<<dim3(4, 3), 256, 0, stream>>>(Wz, Wr, Wh, bz, br, bh,
                                                W_tok, b_tok, start_e, Pz, Pr, Ph);
    init_misc<<<32, 256, 0, stream>>>(tokidx, rcb, ntb);

    // ---- encoder: h0 = x @ W_enc + b_enc (K=2048, 128x256 tiles) ----
    gemm_bt<<<dim3(4, 64), 256, 0, stream>>>(
        x_hi, x_lo, we_hi, we_lo, we_hi, we_lo,
        b_enc, b_enc, nullptr,
        nullptr, hbuf, nullptr, h_hi, h_lo, 256, 0);

    for (int t = 0; t < T_; ++t) {
        // z = sigmoid(h@Wz_bot + Pz[tok]); rh = sigmoid(h@Wr_bot + Pr[tok]) * h
        gemm_bt<<<dim3(8, 64), 256, 0, stream>>>(
            h_hi, h_lo, wzb_hi, wzb_lo, wrb_hi, wrb_lo,
            Pz, Pr, tokidx,
            nullptr, hbuf, zbuf, rh_hi, rh_lo, 128, 1);
        // h = (1-z)h + z*tanh(rh@Wh_bot + Ph[tok])
        gemm_bt<<<dim3(4, 64), 256, 0, stream>>>(
            rh_hi, rh_lo, whb_hi, whb_lo, whb_hi, whb_lo,
            Ph, Ph, tokidx,
            zbuf, hbuf, nullptr, h_hi, h_lo, 128, 2);
        // logits / gumbel argmax / outputs / tokidx
        step_tok<<<B_ / 4, 256, 0, stream>>>(
            hbuf, W_out, b_out, u_noise + (size_t)t * B_ * V_,
            rcb, ntb, tokidx, out_msg,
            out_logits + (size_t)t * B_ * V_, out_nt, t);
    }
}

// Round 6
// 1838.690 us; speedup vs baseline: 2.7006x; 2.7006x over previous
//
#include <hip/hip_runtime.h>
#include <math.h>

#define B_ 8192
#define DIN_ 2048
#define H_ 1024
#define V_ 6
#define T_ 6

typedef short bf16x8 __attribute__((ext_vector_type(8)));
typedef float f32x4 __attribute__((ext_vector_type(4)));

__device__ __forceinline__ unsigned short f32_bf16(float f) {
    unsigned u = __float_as_uint(f);
    u += 0x7FFFu + ((u >> 16) & 1u);
    return (unsigned short)(u >> 16);
}
__device__ __forceinline__ float bf16_f32(unsigned short h) {
    return __uint_as_float(((unsigned)h) << 16);
}

// ---------------------------------------------------------------------------
// conv_w: full 2048x1024 f32 W -> fragment planes, NKB=256 (W_enc only).
// plane addr (halves) = ((n>>4)*NKB + kb)*128 + (n&15)*8 + k8
// ---------------------------------------------------------------------------
__global__ __launch_bounds__(256) void conv_w(const float* __restrict__ W,
        unsigned short* __restrict__ hi, unsigned short* __restrict__ lo)
{
    const int t = blockIdx.x * 256 + threadIdx.x;   // 256K
    const int n = t & 1023;
    const int kb = t >> 10;                          // 0..255
    unsigned hq[4], lq[4];
#pragma unroll
    for (int p = 0; p < 4; ++p) {
        const float v0 = W[(size_t)(kb * 8 + 2 * p) * 1024 + n];
        const float v1 = W[(size_t)(kb * 8 + 2 * p + 1) * 1024 + n];
        const unsigned short h0 = f32_bf16(v0), h1 = f32_bf16(v1);
        const unsigned short l0 = f32_bf16(v0 - bf16_f32(h0));
        const unsigned short l1 = f32_bf16(v1 - bf16_f32(h1));
        hq[p] = (unsigned)h0 | ((unsigned)h1 << 16);
        lq[p] = (unsigned)l0 | ((unsigned)l1 << 16);
    }
    const size_t c = ((size_t)(n >> 4) * 256 + kb) * 128 + (size_t)(n & 15) * 8;
    *(uint4*)(hi + c) = make_uint4(hq[0], hq[1], hq[2], hq[3]);
    *(uint4*)(lo + c) = make_uint4(lq[0], lq[1], lq[2], lq[3]);
}

// ---------------------------------------------------------------------------
// conv_wb: BOTTOM half (rows 1024..2047) of 2048x1024 W -> planes, NKB=128.
// ---------------------------------------------------------------------------
__global__ __launch_bounds__(256) void conv_wb(const float* __restrict__ W,
        unsigned short* __restrict__ hi, unsigned short* __restrict__ lo)
{
    const int t = blockIdx.x * 256 + threadIdx.x;   // 128K
    const int n = t & 1023;
    const int kb = t >> 10;                          // 0..127
    unsigned hq[4], lq[4];
#pragma unroll
    for (int p = 0; p < 4; ++p) {
        const float v0 = W[(size_t)(1024 + kb * 8 + 2 * p) * 1024 + n];
        const float v1 = W[(size_t)(1024 + kb * 8 + 2 * p + 1) * 1024 + n];
        const unsigned short h0 = f32_bf16(v0), h1 = f32_bf16(v1);
        const unsigned short l0 = f32_bf16(v0 - bf16_f32(h0));
        const unsigned short l1 = f32_bf16(v1 - bf16_f32(h1));
        hq[p] = (unsigned)h0 | ((unsigned)h1 << 16);
        lq[p] = (unsigned)l0 | ((unsigned)l1 << 16);
    }
    const size_t c = ((size_t)(n >> 4) * 128 + kb) * 128 + (size_t)(n & 15) * 8;
    *(uint4*)(hi + c) = make_uint4(hq[0], hq[1], hq[2], hq[3]);
    *(uint4*)(lo + c) = make_uint4(lq[0], lq[1], lq[2], lq[3]);
}

// ---------------------------------------------------------------------------
// conv_x: x (8192x2048 f32) -> A planes, NKB=256.
// ---------------------------------------------------------------------------
__global__ __launch_bounds__(256) void conv_x(const float* __restrict__ X,
        unsigned short* __restrict__ hi, unsigned short* __restrict__ lo)
{
    const size_t t = (size_t)blockIdx.x * 256 + threadIdx.x;  // 8192*256
    const int kb = (int)(t & 255);
    const int m = (int)(t >> 8);
    const float4 f0 = *(const float4*)(X + (size_t)m * 2048 + kb * 8);
    const float4 f1 = *(const float4*)(X + (size_t)m * 2048 + kb * 8 + 4);
    const float v[8] = {f0.x, f0.y, f0.z, f0.w, f1.x, f1.y, f1.z, f1.w};
    unsigned hq[4], lq[4];
#pragma unroll
    for (int p = 0; p < 4; ++p) {
        const unsigned short h0 = f32_bf16(v[2 * p]);
        const unsigned short h1 = f32_bf16(v[2 * p + 1]);
        const unsigned short l0 = f32_bf16(v[2 * p] - bf16_f32(h0));
        const unsigned short l1 = f32_bf16(v[2 * p + 1] - bf16_f32(h1));
        hq[p] = (unsigned)h0 | ((unsigned)h1 << 16);
        lq[p] = (unsigned)l0 | ((unsigned)l1 << 16);
    }
    const size_t c = ((size_t)(m >> 4) * 256 + kb) * 128 + (size_t)(m & 15) * 8;
    *(uint4*)(hi + c) = make_uint4(hq[0], hq[1], hq[2], hq[3]);
    *(uint4*)(lo + c) = make_uint4(lq[0], lq[1], lq[2], lq[3]);
}

// ---------------------------------------------------------------------------
// prep_tables: P_m[tok][n] = sum_k emb[tok][k] * W_m[k][n] + b_m[n]
// ---------------------------------------------------------------------------
__global__ __launch_bounds__(256) void prep_tables(
        const float* __restrict__ Wz, const float* __restrict__ Wr,
        const float* __restrict__ Wh,
        const float* __restrict__ bz, const float* __restrict__ br,
        const float* __restrict__ bh,
        const float* __restrict__ Wt, const float* __restrict__ bt,
        const float* __restrict__ se,
        float* __restrict__ Pz, float* __restrict__ Pr, float* __restrict__ Ph)
{
    __shared__ float emb[7][1024];
    const int tid = threadIdx.x;
    for (int i = tid; i < 7 * 1024; i += 256) {
        const int r = i >> 10, k = i & 1023;
        emb[r][k] = (r < 6) ? (Wt[(size_t)r * 1024 + k] + bt[k]) : se[k];
    }
    __syncthreads();
    const float* W = (blockIdx.y == 0) ? Wz : ((blockIdx.y == 1) ? Wr : Wh);
    const float* bb = (blockIdx.y == 0) ? bz : ((blockIdx.y == 1) ? br : bh);
    float* P = (blockIdx.y == 0) ? Pz : ((blockIdx.y == 1) ? Pr : Ph);
    const int n = blockIdx.x * 256 + tid;
    float acc[7] = {0.f, 0.f, 0.f, 0.f, 0.f, 0.f, 0.f};
    for (int k = 0; k < 1024; ++k) {
        const float wv = W[(size_t)k * 1024 + n];
#pragma unroll
        for (int r = 0; r < 7; ++r) acc[r] = fmaf(emb[r][k], wv, acc[r]);
    }
    const float bvv = bb[n];
#pragma unroll
    for (int r = 0; r < 7; ++r) P[(size_t)r * 1024 + n] = acc[r] + bvv;
}

// ---------------------------------------------------------------------------
// init_misc: tokidx = 6 (start), rc = 1, nt = 0.
// ---------------------------------------------------------------------------
__global__ __launch_bounds__(256) void init_misc(
        int* __restrict__ tokidx, float* __restrict__ rc, float* __restrict__ nt)
{
    const int t = blockIdx.x * 256 + threadIdx.x;   // 8192
    tokidx[t] = 6;
    rc[t] = 1.0f;
    nt[t] = 0.0f;
}

// ---------------------------------------------------------------------------
// gemm_bt: 128x128 tile, BK=32, split-bf16 3-pass MFMA, register-prefetch
// software pipeline (8 uint4 in flight, ~160 total regs — round 5's 128x256
// variant spilled at ~250 regs: WRITE_SIZE 70MB -> 2.2GB scratch traffic).
// Per step: ds_write staged regs (vmcnt wait for loads issued one step ago
// lands here, hidden by the intervening 48 MFMA + ds_reads), barrier, issue
// next step's loads, compute.
//   mode 0: encoder. nkb=256. v = acc + P0[col] (P0 = b_enc, toks=0).
//   mode 1: z/r (grid.x=16). nkb=128. bx<8: z=sigmoid->outf; bx>=8: rh->planes.
//   mode 2: nkb=128. h = (1-z)h + z*tanh(acc + Ph[tok]) -> hbuf + planes.
// ---------------------------------------------------------------------------
__global__ __launch_bounds__(256, 2)
void gemm_bt(
    const unsigned short* __restrict__ A_hi, const unsigned short* __restrict__ A_lo,
    const unsigned short* __restrict__ B0_hi, const unsigned short* __restrict__ B0_lo,
    const unsigned short* __restrict__ B1_hi, const unsigned short* __restrict__ B1_lo,
    const float* __restrict__ P0, const float* __restrict__ P1,
    const int* __restrict__ tokidx,
    const float* __restrict__ zbuf, float* __restrict__ hbuf,
    float* __restrict__ outf,
    unsigned short* __restrict__ ophi, unsigned short* __restrict__ oplo,
    int nkb, int mode)
{
    __shared__ unsigned short lds[16384];   // 32KB: Ahi|Alo|Bhi|Blo

    const int tid = threadIdx.x;
    const int lane = tid & 63;
    const int w = tid >> 6;

    // XCD-aware swizzle (bijective relabel of NX x 64 grid)
    const int NX = gridDim.x;
    const int lin = blockIdx.y * NX + blockIdx.x;
    const int xcd = lin & 7;
    const int idx = lin >> 3;
    int bx = idx % NX;
    const int by = xcd * 8 + idx / NX;

    const unsigned short* Bhi = B0_hi;
    const unsigned short* Blo = B0_lo;
    const float* Pm = P0;
    int isR = 0;
    if (mode == 1 && bx >= 8) { bx -= 8; Bhi = B1_hi; Blo = B1_lo; Pm = P1; isR = 1; }

    const int m0 = by * 128;
    const int n0 = bx * 128;
    const int SD = nkb * 128;               // subtile stride (halves)

    // global base pointers (wave w stages subtiles 2w, 2w+1)
    const size_t aoff = ((size_t)(by * 8 + 2 * w) * nkb) * 128 + lane * 8;
    const unsigned short* pAh = A_hi + aoff;
    const unsigned short* pAl = A_lo + aoff;
    const size_t boff = ((size_t)(bx * 8 + 2 * w) * nkb) * 128 + lane * 8;
    const unsigned short* pBh = Bhi + boff;
    const unsigned short* pBl = Blo + boff;

    // LDS write destinations
    unsigned short* dA0h = lds + (2 * w) * 512 + lane * 8;
    unsigned short* dA1h = dA0h + 512;
    unsigned short* dA0l = dA0h + 4096;
    unsigned short* dA1l = dA0l + 512;
    unsigned short* dB0h = dA0h + 8192;
    unsigned short* dB1h = dB0h + 512;
    unsigned short* dB0l = dA0h + 12288;
    unsigned short* dB1l = dB0l + 512;

    f32x4 acc[4][4];
#pragma unroll
    for (int i = 0; i < 4; ++i)
#pragma unroll
        for (int j = 0; j < 4; ++j) acc[i][j] = (f32x4){0.f, 0.f, 0.f, 0.f};

    const int wr = w >> 1, wc = w & 1;
    const int fq = lane >> 4;
    const int fm = lane & 15;
    const int nsteps = nkb >> 2;

    // prefetch step 0
    uint4 rA0h = *(const uint4*)(pAh);
    uint4 rA1h = *(const uint4*)(pAh + SD);
    uint4 rA0l = *(const uint4*)(pAl);
    uint4 rA1l = *(const uint4*)(pAl + SD);
    uint4 rB0h = *(const uint4*)(pBh);
    uint4 rB1h = *(const uint4*)(pBh + SD);
    uint4 rB0l = *(const uint4*)(pBl);
    uint4 rB1l = *(const uint4*)(pBl + SD);

#pragma unroll 1
    for (int s = 0; s < nsteps; ++s) {
        __syncthreads();
        *(uint4*)dA0h = rA0h;
        *(uint4*)dA1h = rA1h;
        *(uint4*)dA0l = rA0l;
        *(uint4*)dA1l = rA1l;
        *(uint4*)dB0h = rB0h;
        *(uint4*)dB1h = rB1h;
        *(uint4*)dB0l = rB0l;
        *(uint4*)dB1l = rB1l;
        __syncthreads();

        if (s + 1 < nsteps) {
            const int so = (s + 1) * 512;
            rA0h = *(const uint4*)(pAh + so);
            rA1h = *(const uint4*)(pAh + SD + so);
            rA0l = *(const uint4*)(pAl + so);
            rA1l = *(const uint4*)(pAl + SD + so);
            rB0h = *(const uint4*)(pBh + so);
            rB1h = *(const uint4*)(pBh + SD + so);
            rB0l = *(const uint4*)(pBl + so);
            rB1l = *(const uint4*)(pBl + SD + so);
        }

        bf16x8 ah[4], al[4], bh4[4], bl4[4];
#pragma unroll
        for (int i = 0; i < 4; ++i) {
            const int ra = (wr * 4 + i) * 512 + fq * 128 + fm * 8;
            ah[i] = *(const bf16x8*)(lds + ra);
            al[i] = *(const bf16x8*)(lds + 4096 + ra);
            const int rb = (wc * 4 + i) * 512 + fq * 128 + fm * 8;
            bh4[i] = *(const bf16x8*)(lds + 8192 + rb);
            bl4[i] = *(const bf16x8*)(lds + 12288 + rb);
        }
#pragma unroll
        for (int i = 0; i < 4; ++i)
#pragma unroll
            for (int j = 0; j < 4; ++j) {
                acc[i][j] = __builtin_amdgcn_mfma_f32_16x16x32_bf16(ah[i], bh4[j], acc[i][j], 0, 0, 0);
                acc[i][j] = __builtin_amdgcn_mfma_f32_16x16x32_bf16(ah[i], bl4[j], acc[i][j], 0, 0, 0);
                acc[i][j] = __builtin_amdgcn_mfma_f32_16x16x32_bf16(al[i], bh4[j], acc[i][j], 0, 0, 0);
            }
    }

    // ---- epilogue ----
#pragma unroll
    for (int i = 0; i < 4; ++i) {
        int toks[4];
#pragma unroll
        for (int r = 0; r < 4; ++r) {
            const int row = m0 + wr * 64 + i * 16 + fq * 4 + r;
            toks[r] = tokidx ? tokidx[row] : 0;
        }
#pragma unroll
        for (int j = 0; j < 4; ++j) {
            const int col = n0 + wc * 64 + j * 16 + fm;
#pragma unroll
            for (int r = 0; r < 4; ++r) {
                const int row = m0 + wr * 64 + i * 16 + fq * 4 + r;
                const float v = acc[i][j][r] + Pm[(size_t)toks[r] * 1024 + col];
                const size_t off = (size_t)row * 1024 + col;
                const size_t pc = ((size_t)(row >> 4) * 128 + (col >> 3)) * 128
                                  + (size_t)(row & 15) * 8 + (col & 7);
                if (mode == 0) {
                    hbuf[off] = v;
                    const unsigned short hv = f32_bf16(v);
                    ophi[pc] = hv;
                    oplo[pc] = f32_bf16(v - bf16_f32(hv));
                } else if (mode == 1) {
                    const float sg = 1.0f / (1.0f + expf(-v));
                    if (!isR) {
                        outf[off] = sg;
                    } else {
                        const float rh = sg * hbuf[off];
                        const unsigned short hv = f32_bf16(rh);
                        ophi[pc] = hv;
                        oplo[pc] = f32_bf16(rh - bf16_f32(hv));
                    }
                } else {
                    const float tv = tanhf(v);
                    const float zv = zbuf[off];
                    const float hn = (1.0f - zv) * hbuf[off] + zv * tv;
                    hbuf[off] = hn;
                    const unsigned short hv = f32_bf16(hn);
                    ophi[pc] = hv;
                    oplo[pc] = f32_bf16(hn - bf16_f32(hv));
                }
            }
        }
    }
}

// ---------------------------------------------------------------------------
// step_tok: one wave per batch row.
// ---------------------------------------------------------------------------
__global__ __launch_bounds__(256)
void step_tok(const float* __restrict__ h,
              const float* __restrict__ W_out, const float* __restrict__ b_out,
              const float* __restrict__ u,
              float* __restrict__ rc, float* __restrict__ nt,
              int* __restrict__ tokidx,
              float* __restrict__ out_msg, float* __restrict__ out_logits,
              float* __restrict__ out_nt, int t)
{
    const int lane = threadIdx.x & 63;
    const int wv = threadIdx.x >> 6;
    const int b = blockIdx.x * 4 + wv;

    const float* hr = h + (size_t)b * H_;
    float s[6] = {0.f, 0.f, 0.f, 0.f, 0.f, 0.f};
#pragma unroll
    for (int i = 0; i < 4; ++i) {
        const int k0 = i * 256 + lane * 4;
        const float4 hv = *(const float4*)(hr + k0);
        const float he[4] = {hv.x, hv.y, hv.z, hv.w};
#pragma unroll
        for (int e = 0; e < 4; ++e) {
            const float* wp = W_out + (size_t)(k0 + e) * V_;
            const float xv = he[e];
#pragma unroll
            for (int v = 0; v < 6; ++v) s[v] = fmaf(xv, wp[v], s[v]);
        }
    }
#pragma unroll
    for (int m = 1; m < 64; m <<= 1) {
#pragma unroll
        for (int v = 0; v < 6; ++v) s[v] += __shfl_xor(s[v], m, 64);
    }

    float lg[6];
#pragma unroll
    for (int v = 0; v < 6; ++v) lg[v] = s[v] + b_out[v];

    const float* ub = u + (size_t)b * V_;
    const float eps = 1e-10f;
    float aa[6];
#pragma unroll
    for (int v = 0; v < 6; ++v) {
        const float g = -logf(-logf(ub[v] + eps) + eps);
        aa[v] = lg[v] + g;  // TAU = 1
    }
    int tok = 0;
    float best = aa[0];
#pragma unroll
    for (int v = 1; v < 6; ++v)
        if (aa[v] > best) { best = aa[v]; tok = v; }

    if (lane == 0) {
        const float rco = rc[b];
#pragma unroll
        for (int v = 0; v < 6; ++v) out_logits[(size_t)b * 6 + v] = lg[v];
#pragma unroll
        for (int v = 0; v < 6; ++v)
            out_msg[(size_t)b * 36 + t * 6 + v] = (v == tok) ? rco : 0.0f;
        const float ntn = nt[b] + rco;
        nt[b] = ntn;
        out_nt[b] = ntn;
        rc[b] = (tok == 5) ? 0.0f : rco;
        tokidx[b] = tok;
    }
}

// ---------------------------------------------------------------------------
extern "C" void kernel_launch(void* const* d_in, const int* in_sizes, int n_in,
                              void* d_out, int out_size, void* d_ws, size_t ws_size,
                              hipStream_t stream)
{
    (void)in_sizes; (void)n_in; (void)out_size; (void)ws_size;
    const float* x       = (const float*)d_in[0];
    const float* u_noise = (const float*)d_in[1];
    const float* W_enc   = (const float*)d_in[2];
    const float* b_enc   = (const float*)d_in[3];
    const float* start_e = (const float*)d_in[4];
    const float* W_tok   = (const float*)d_in[5];
    const float* b_tok   = (const float*)d_in[6];
    const float* Wz      = (const float*)d_in[7];
    const float* bz      = (const float*)d_in[8];
    const float* Wr      = (const float*)d_in[9];
    const float* br      = (const float*)d_in[10];
    const float* Wh      = (const float*)d_in[11];
    const float* bh      = (const float*)d_in[12];
    const float* W_out   = (const float*)d_in[13];
    const float* b_out   = (const float*)d_in[14];

    float* out = (float*)d_out;
    float* out_msg = out;                                   // (B, T*V)
    float* out_logits = out + (size_t)B_ * T_ * V_;         // (T, B, V)
    float* out_nt = out_logits + (size_t)T_ * B_ * V_;      // (B,)

    // ---- workspace layout (~148.1 MB) ----
    char* wsb = (char*)d_ws;
    const size_t MB = 1024 * 1024;
    unsigned short* wzb_hi = (unsigned short*)(wsb + 0 * MB);    // 2MB each
    unsigned short* wzb_lo = (unsigned short*)(wsb + 2 * MB);
    unsigned short* wrb_hi = (unsigned short*)(wsb + 4 * MB);
    unsigned short* wrb_lo = (unsigned short*)(wsb + 6 * MB);
    unsigned short* whb_hi = (unsigned short*)(wsb + 8 * MB);
    unsigned short* whb_lo = (unsigned short*)(wsb + 10 * MB);
    unsigned short* we_hi  = (unsigned short*)(wsb + 12 * MB);   // 4MB
    unsigned short* we_lo  = (unsigned short*)(wsb + 16 * MB);   // 4MB
    unsigned short* x_hi   = (unsigned short*)(wsb + 20 * MB);   // 32MB
    unsigned short* x_lo   = (unsigned short*)(wsb + 52 * MB);   // 32MB
    float*  zbuf  = (float*)(wsb + 20 * MB);                     // alias x_hi
    unsigned short* rh_hi  = (unsigned short*)(wsb + 52 * MB);   // alias x_lo
    unsigned short* rh_lo  = (unsigned short*)(wsb + 68 * MB);
    float*  hbuf  = (float*)(wsb + 84 * MB);                     // 32MB
    unsigned short* h_hi   = (unsigned short*)(wsb + 116 * MB);  // 16MB
    unsigned short* h_lo   = (unsigned short*)(wsb + 132 * MB);  // 16MB
    float* Pz = (float*)(wsb + 148 * MB);                        // 7x1024 each
    float* Pr = Pz + 7 * 1024;
    float* Ph = Pr + 7 * 1024;
    int* tokidx = (int*)(Ph + 7 * 1024);
    float* rcb = (float*)(tokidx + B_);
    float* ntb = rcb + B_;

    // ---- one-time conversions / tables ----
    conv_wb<<<512, 256, 0, stream>>>(Wz, wzb_hi, wzb_lo);
    conv_wb<<<512, 256, 0, stream>>>(Wr, wrb_hi, wrb_lo);
    conv_wb<<<512, 256, 0, stream>>>(Wh, whb_hi, whb_lo);
    conv_w<<<1024, 256, 0, stream>>>(W_enc, we_hi, we_lo);
    conv_x<<<8192, 256, 0, stream>>>(x, x_hi, x_lo);
    prep_tables<<<dim3(4, 3), 256, 0, stream>>>(Wz, Wr, Wh, bz, br, bh,
                                                W_tok, b_tok, start_e, Pz, Pr, Ph);
    init_misc<<<32, 256, 0, stream>>>(tokidx, rcb, ntb);

    // ---- encoder: h0 = x @ W_enc + b_enc (K=2048) ----
    gemm_bt<<<dim3(8, 64), 256, 0, stream>>>(
        x_hi, x_lo, we_hi, we_lo, nullptr, nullptr,
        b_enc, nullptr, nullptr,
        nullptr, hbuf, nullptr, h_hi, h_lo, 256, 0);

    for (int t = 0; t < T_; ++t) {
        // z = sigmoid(h@Wz_bot + Pz[tok]); rh = sigmoid(h@Wr_bot + Pr[tok]) * h
        gemm_bt<<<dim3(16, 64), 256, 0, stream>>>(
            h_hi, h_lo, wzb_hi, wzb_lo, wrb_hi, wrb_lo,
            Pz, Pr, tokidx,
            nullptr, hbuf, zbuf, rh_hi, rh_lo, 128, 1);
        // h = (1-z)h + z*tanh(rh@Wh_bot + Ph[tok])
        gemm_bt<<<dim3(8, 64), 256, 0, stream>>>(
            rh_hi, rh_lo, whb_hi, whb_lo, nullptr, nullptr,
            Ph, nullptr, tokidx,
            zbuf, hbuf, nullptr, h_hi, h_lo, 128, 2);
        // logits / gumbel argmax / outputs / tokidx
        step_tok<<<B_ / 4, 256, 0, stream>>>(
            hbuf, W_out, b_out, u_noise + (size_t)t * B_ * V_,
            rcb, ntb, tokidx, out_msg,
            out_logits + (size_t)t * B_ * V_, out_nt, t);
    }
}

// Round 7
// 1828.613 us; speedup vs baseline: 2.7155x; 1.0055x over previous
//
#include <hip/hip_runtime.h>
#include <math.h>

#define B_ 8192
#define DIN_ 2048
#define H_ 1024
#define V_ 6
#define T_ 6

typedef short bf16x8 __attribute__((ext_vector_type(8)));
typedef float f32x4 __attribute__((ext_vector_type(4)));

__device__ __forceinline__ unsigned short f32_bf16(float f) {
    unsigned u = __float_as_uint(f);
    u += 0x7FFFu + ((u >> 16) & 1u);
    return (unsigned short)(u >> 16);
}
__device__ __forceinline__ float bf16_f32(unsigned short h) {
    return __uint_as_float(((unsigned)h) << 16);
}

// ---------------------------------------------------------------------------
// conv_w: full 2048x1024 f32 W -> fragment planes, NKB=256 (W_enc only).
// plane addr (halves) = ((n>>4)*NKB + kb)*128 + (n&15)*8 + k8
// ---------------------------------------------------------------------------
__global__ __launch_bounds__(256) void conv_w(const float* __restrict__ W,
        unsigned short* __restrict__ hi, unsigned short* __restrict__ lo)
{
    const int t = blockIdx.x * 256 + threadIdx.x;   // 256K
    const int n = t & 1023;
    const int kb = t >> 10;                          // 0..255
    unsigned hq[4], lq[4];
#pragma unroll
    for (int p = 0; p < 4; ++p) {
        const float v0 = W[(size_t)(kb * 8 + 2 * p) * 1024 + n];
        const float v1 = W[(size_t)(kb * 8 + 2 * p + 1) * 1024 + n];
        const unsigned short h0 = f32_bf16(v0), h1 = f32_bf16(v1);
        const unsigned short l0 = f32_bf16(v0 - bf16_f32(h0));
        const unsigned short l1 = f32_bf16(v1 - bf16_f32(h1));
        hq[p] = (unsigned)h0 | ((unsigned)h1 << 16);
        lq[p] = (unsigned)l0 | ((unsigned)l1 << 16);
    }
    const size_t c = ((size_t)(n >> 4) * 256 + kb) * 128 + (size_t)(n & 15) * 8;
    *(uint4*)(hi + c) = make_uint4(hq[0], hq[1], hq[2], hq[3]);
    *(uint4*)(lo + c) = make_uint4(lq[0], lq[1], lq[2], lq[3]);
}

// ---------------------------------------------------------------------------
// conv_wb: BOTTOM half (rows 1024..2047) of 2048x1024 W -> planes, NKB=128.
// ---------------------------------------------------------------------------
__global__ __launch_bounds__(256) void conv_wb(const float* __restrict__ W,
        unsigned short* __restrict__ hi, unsigned short* __restrict__ lo)
{
    const int t = blockIdx.x * 256 + threadIdx.x;   // 128K
    const int n = t & 1023;
    const int kb = t >> 10;                          // 0..127
    unsigned hq[4], lq[4];
#pragma unroll
    for (int p = 0; p < 4; ++p) {
        const float v0 = W[(size_t)(1024 + kb * 8 + 2 * p) * 1024 + n];
        const float v1 = W[(size_t)(1024 + kb * 8 + 2 * p + 1) * 1024 + n];
        const unsigned short h0 = f32_bf16(v0), h1 = f32_bf16(v1);
        const unsigned short l0 = f32_bf16(v0 - bf16_f32(h0));
        const unsigned short l1 = f32_bf16(v1 - bf16_f32(h1));
        hq[p] = (unsigned)h0 | ((unsigned)h1 << 16);
        lq[p] = (unsigned)l0 | ((unsigned)l1 << 16);
    }
    const size_t c = ((size_t)(n >> 4) * 128 + kb) * 128 + (size_t)(n & 15) * 8;
    *(uint4*)(hi + c) = make_uint4(hq[0], hq[1], hq[2], hq[3]);
    *(uint4*)(lo + c) = make_uint4(lq[0], lq[1], lq[2], lq[3]);
}

// ---------------------------------------------------------------------------
// conv_x: x (8192x2048 f32) -> A planes, NKB=256.
// ---------------------------------------------------------------------------
__global__ __launch_bounds__(256) void conv_x(const float* __restrict__ X,
        unsigned short* __restrict__ hi, unsigned short* __restrict__ lo)
{
    const size_t t = (size_t)blockIdx.x * 256 + threadIdx.x;  // 8192*256
    const int kb = (int)(t & 255);
    const int m = (int)(t >> 8);
    const float4 f0 = *(const float4*)(X + (size_t)m * 2048 + kb * 8);
    const float4 f1 = *(const float4*)(X + (size_t)m * 2048 + kb * 8 + 4);
    const float v[8] = {f0.x, f0.y, f0.z, f0.w, f1.x, f1.y, f1.z, f1.w};
    unsigned hq[4], lq[4];
#pragma unroll
    for (int p = 0; p < 4; ++p) {
        const unsigned short h0 = f32_bf16(v[2 * p]);
        const unsigned short h1 = f32_bf16(v[2 * p + 1]);
        const unsigned short l0 = f32_bf16(v[2 * p] - bf16_f32(h0));
        const unsigned short l1 = f32_bf16(v[2 * p + 1] - bf16_f32(h1));
        hq[p] = (unsigned)h0 | ((unsigned)h1 << 16);
        lq[p] = (unsigned)l0 | ((unsigned)l1 << 16);
    }
    const size_t c = ((size_t)(m >> 4) * 256 + kb) * 128 + (size_t)(m & 15) * 8;
    *(uint4*)(hi + c) = make_uint4(hq[0], hq[1], hq[2], hq[3]);
    *(uint4*)(lo + c) = make_uint4(lq[0], lq[1], lq[2], lq[3]);
}

// ---------------------------------------------------------------------------
// prep_tables: P_m[tok][n] = sum_k emb[tok][k] * W_m[k][n] + b_m[n]
// ---------------------------------------------------------------------------
__global__ __launch_bounds__(256) void prep_tables(
        const float* __restrict__ Wz, const float* __restrict__ Wr,
        const float* __restrict__ Wh,
        const float* __restrict__ bz, const float* __restrict__ br,
        const float* __restrict__ bh,
        const float* __restrict__ Wt, const float* __restrict__ bt,
        const float* __restrict__ se,
        float* __restrict__ Pz, float* __restrict__ Pr, float* __restrict__ Ph)
{
    __shared__ float emb[7][1024];
    const int tid = threadIdx.x;
    for (int i = tid; i < 7 * 1024; i += 256) {
        const int r = i >> 10, k = i & 1023;
        emb[r][k] = (r < 6) ? (Wt[(size_t)r * 1024 + k] + bt[k]) : se[k];
    }
    __syncthreads();
    const float* W = (blockIdx.y == 0) ? Wz : ((blockIdx.y == 1) ? Wr : Wh);
    const float* bb = (blockIdx.y == 0) ? bz : ((blockIdx.y == 1) ? br : bh);
    float* P = (blockIdx.y == 0) ? Pz : ((blockIdx.y == 1) ? Pr : Ph);
    const int n = blockIdx.x * 256 + tid;
    float acc[7] = {0.f, 0.f, 0.f, 0.f, 0.f, 0.f, 0.f};
    for (int k = 0; k < 1024; ++k) {
        const float wv = W[(size_t)k * 1024 + n];
#pragma unroll
        for (int r = 0; r < 7; ++r) acc[r] = fmaf(emb[r][k], wv, acc[r]);
    }
    const float bvv = bb[n];
#pragma unroll
    for (int r = 0; r < 7; ++r) P[(size_t)r * 1024 + n] = acc[r] + bvv;
}

// ---------------------------------------------------------------------------
// init_misc: tokidx = 6 (start), rc = 1, nt = 0.
// ---------------------------------------------------------------------------
__global__ __launch_bounds__(256) void init_misc(
        int* __restrict__ tokidx, float* __restrict__ rc, float* __restrict__ nt)
{
    const int t = blockIdx.x * 256 + threadIdx.x;   // 8192
    tokidx[t] = 6;
    rc[t] = 1.0f;
    nt[t] = 0.0f;
}

// ---------------------------------------------------------------------------
// gemm_bt: 128x128 tile, BK=32, split-bf16 3-pass MFMA.
// LDS DOUBLE-BUFFER pipeline, ONE barrier per step:
//   step s: ds_read frags from buf[p] -> MFMA;
//           ds_write buf[1-p] with regs loaded at step s-1 (vmcnt wait is
//           off the critical path: loads stay in flight across the barrier
//           since they target VGPRs, not LDS — no forced drain);
//           issue loads for step s+2; barrier.
// Round-6 evidence: 2-barrier chain left ~5900 cyc/slot vs ~1500 of work.
//   mode 0: encoder. nkb=256. v = acc + P0[col] (toks=0).
//   mode 1: z/r (grid.x=16). nkb=128. bx<8: z=sigmoid->outf; bx>=8: rh->planes.
//   mode 2: nkb=128. h = (1-z)h + z*tanh(acc + Ph[tok]) -> hbuf + planes.
// ---------------------------------------------------------------------------
__global__ __launch_bounds__(256, 2)
void gemm_bt(
    const unsigned short* __restrict__ A_hi, const unsigned short* __restrict__ A_lo,
    const unsigned short* __restrict__ B0_hi, const unsigned short* __restrict__ B0_lo,
    const unsigned short* __restrict__ B1_hi, const unsigned short* __restrict__ B1_lo,
    const float* __restrict__ P0, const float* __restrict__ P1,
    const int* __restrict__ tokidx,
    const float* __restrict__ zbuf, float* __restrict__ hbuf,
    float* __restrict__ outf,
    unsigned short* __restrict__ ophi, unsigned short* __restrict__ oplo,
    int nkb, int mode)
{
    // 64KB: two 32KB buffers, each Ahi|Alo|Bhi|Blo (4096 halves apiece)
    __shared__ unsigned short lds[32768];

    const int tid = threadIdx.x;
    const int lane = tid & 63;
    const int w = tid >> 6;

    // XCD-aware swizzle (bijective relabel of NX x 64 grid)
    const int NX = gridDim.x;
    const int lin = blockIdx.y * NX + blockIdx.x;
    const int xcd = lin & 7;
    const int idx = lin >> 3;
    int bx = idx % NX;
    const int by = xcd * 8 + idx / NX;

    const unsigned short* Bhi = B0_hi;
    const unsigned short* Blo = B0_lo;
    const float* Pm = P0;
    int isR = 0;
    if (mode == 1 && bx >= 8) { bx -= 8; Bhi = B1_hi; Blo = B1_lo; Pm = P1; isR = 1; }

    const int m0 = by * 128;
    const int n0 = bx * 128;
    const int SD = nkb * 128;               // subtile stride (halves)

    // global base pointers (wave w stages subtiles 2w, 2w+1)
    const size_t aoff = ((size_t)(by * 8 + 2 * w) * nkb) * 128 + lane * 8;
    const unsigned short* pAh = A_hi + aoff;
    const unsigned short* pAl = A_lo + aoff;
    const size_t boff = ((size_t)(bx * 8 + 2 * w) * nkb) * 128 + lane * 8;
    const unsigned short* pBh = Bhi + boff;
    const unsigned short* pBl = Blo + boff;

    // LDS write base within a buffer (halves)
    const int wbase = 2 * w * 512 + lane * 8;

    f32x4 acc[4][4];
#pragma unroll
    for (int i = 0; i < 4; ++i)
#pragma unroll
        for (int j = 0; j < 4; ++j) acc[i][j] = (f32x4){0.f, 0.f, 0.f, 0.f};

    const int wr = w >> 1, wc = w & 1;
    const int fq = lane >> 4;
    const int fm = lane & 15;
    const int nsteps = nkb >> 2;

    // ---- prologue: load step0, write buf0, load step1 ----
    uint4 rA0h = *(const uint4*)(pAh);
    uint4 rA1h = *(const uint4*)(pAh + SD);
    uint4 rA0l = *(const uint4*)(pAl);
    uint4 rA1l = *(const uint4*)(pAl + SD);
    uint4 rB0h = *(const uint4*)(pBh);
    uint4 rB1h = *(const uint4*)(pBh + SD);
    uint4 rB0l = *(const uint4*)(pBl);
    uint4 rB1l = *(const uint4*)(pBl + SD);

    *(uint4*)(lds + wbase)               = rA0h;
    *(uint4*)(lds + wbase + 512)         = rA1h;
    *(uint4*)(lds + 4096 + wbase)        = rA0l;
    *(uint4*)(lds + 4096 + wbase + 512)  = rA1l;
    *(uint4*)(lds + 8192 + wbase)        = rB0h;
    *(uint4*)(lds + 8192 + wbase + 512)  = rB1h;
    *(uint4*)(lds + 12288 + wbase)       = rB0l;
    *(uint4*)(lds + 12288 + wbase + 512) = rB1l;

    if (nsteps > 1) {
        rA0h = *(const uint4*)(pAh + 512);
        rA1h = *(const uint4*)(pAh + SD + 512);
        rA0l = *(const uint4*)(pAl + 512);
        rA1l = *(const uint4*)(pAl + SD + 512);
        rB0h = *(const uint4*)(pBh + 512);
        rB1h = *(const uint4*)(pBh + SD + 512);
        rB0l = *(const uint4*)(pBl + 512);
        rB1l = *(const uint4*)(pBl + SD + 512);
    }
    __syncthreads();

#pragma unroll 1
    for (int s = 0; s < nsteps; ++s) {
        const int pb = (s & 1) << 14;       // read-buffer base (halves)
        const int qb = 16384 - pb;          // write-buffer base

        // ---- fragment reads from buf[p] ----
        bf16x8 ah[4], al[4], bh4[4], bl4[4];
#pragma unroll
        for (int i = 0; i < 4; ++i) {
            const int ra = pb + (wr * 4 + i) * 512 + fq * 128 + fm * 8;
            ah[i] = *(const bf16x8*)(lds + ra);
            al[i] = *(const bf16x8*)(lds + 4096 + ra);
            const int rb = pb + 8192 + (wc * 4 + i) * 512 + fq * 128 + fm * 8;
            bh4[i] = *(const bf16x8*)(lds + rb);
            bl4[i] = *(const bf16x8*)(lds + 4096 + rb);
        }

        // ---- write step s+1's data into buf[1-p] (regs loaded at s-1) ----
        if (s + 1 < nsteps) {
            *(uint4*)(lds + qb + wbase)               = rA0h;
            *(uint4*)(lds + qb + wbase + 512)         = rA1h;
            *(uint4*)(lds + qb + 4096 + wbase)        = rA0l;
            *(uint4*)(lds + qb + 4096 + wbase + 512)  = rA1l;
            *(uint4*)(lds + qb + 8192 + wbase)        = rB0h;
            *(uint4*)(lds + qb + 8192 + wbase + 512)  = rB1h;
            *(uint4*)(lds + qb + 12288 + wbase)       = rB0l;
            *(uint4*)(lds + qb + 12288 + wbase + 512) = rB1l;
        }
        // ---- issue loads for step s+2 ----
        if (s + 2 < nsteps) {
            const int so = (s + 2) * 512;
            rA0h = *(const uint4*)(pAh + so);
            rA1h = *(const uint4*)(pAh + SD + so);
            rA0l = *(const uint4*)(pAl + so);
            rA1l = *(const uint4*)(pAl + SD + so);
            rB0h = *(const uint4*)(pBh + so);
            rB1h = *(const uint4*)(pBh + SD + so);
            rB0l = *(const uint4*)(pBl + so);
            rB1l = *(const uint4*)(pBl + SD + so);
        }

        // ---- MFMA ----
#pragma unroll
        for (int i = 0; i < 4; ++i)
#pragma unroll
            for (int j = 0; j < 4; ++j) {
                acc[i][j] = __builtin_amdgcn_mfma_f32_16x16x32_bf16(ah[i], bh4[j], acc[i][j], 0, 0, 0);
                acc[i][j] = __builtin_amdgcn_mfma_f32_16x16x32_bf16(ah[i], bl4[j], acc[i][j], 0, 0, 0);
                acc[i][j] = __builtin_amdgcn_mfma_f32_16x16x32_bf16(al[i], bh4[j], acc[i][j], 0, 0, 0);
            }

        __syncthreads();
    }

    // ---- epilogue ----
#pragma unroll
    for (int i = 0; i < 4; ++i) {
        int toks[4];
#pragma unroll
        for (int r = 0; r < 4; ++r) {
            const int row = m0 + wr * 64 + i * 16 + fq * 4 + r;
            toks[r] = tokidx ? tokidx[row] : 0;
        }
#pragma unroll
        for (int j = 0; j < 4; ++j) {
            const int col = n0 + wc * 64 + j * 16 + fm;
#pragma unroll
            for (int r = 0; r < 4; ++r) {
                const int row = m0 + wr * 64 + i * 16 + fq * 4 + r;
                const float v = acc[i][j][r] + Pm[(size_t)toks[r] * 1024 + col];
                const size_t off = (size_t)row * 1024 + col;
                const size_t pc = ((size_t)(row >> 4) * 128 + (col >> 3)) * 128
                                  + (size_t)(row & 15) * 8 + (col & 7);
                if (mode == 0) {
                    hbuf[off] = v;
                    const unsigned short hv = f32_bf16(v);
                    ophi[pc] = hv;
                    oplo[pc] = f32_bf16(v - bf16_f32(hv));
                } else if (mode == 1) {
                    const float sg = 1.0f / (1.0f + expf(-v));
                    if (!isR) {
                        outf[off] = sg;
                    } else {
                        const float rh = sg * hbuf[off];
                        const unsigned short hv = f32_bf16(rh);
                        ophi[pc] = hv;
                        oplo[pc] = f32_bf16(rh - bf16_f32(hv));
                    }
                } else {
                    const float tv = tanhf(v);
                    const float zv = zbuf[off];
                    const float hn = (1.0f - zv) * hbuf[off] + zv * tv;
                    hbuf[off] = hn;
                    const unsigned short hv = f32_bf16(hn);
                    ophi[pc] = hv;
                    oplo[pc] = f32_bf16(hn - bf16_f32(hv));
                }
            }
        }
    }
}

// ---------------------------------------------------------------------------
// step_tok: one wave per batch row.
// ---------------------------------------------------------------------------
__global__ __launch_bounds__(256)
void step_tok(const float* __restrict__ h,
              const float* __restrict__ W_out, const float* __restrict__ b_out,
              const float* __restrict__ u,
              float* __restrict__ rc, float* __restrict__ nt,
              int* __restrict__ tokidx,
              float* __restrict__ out_msg, float* __restrict__ out_logits,
              float* __restrict__ out_nt, int t)
{
    const int lane = threadIdx.x & 63;
    const int wv = threadIdx.x >> 6;
    const int b = blockIdx.x * 4 + wv;

    const float* hr = h + (size_t)b * H_;
    float s[6] = {0.f, 0.f, 0.f, 0.f, 0.f, 0.f};
#pragma unroll
    for (int i = 0; i < 4; ++i) {
        const int k0 = i * 256 + lane * 4;
        const float4 hv = *(const float4*)(hr + k0);
        const float he[4] = {hv.x, hv.y, hv.z, hv.w};
#pragma unroll
        for (int e = 0; e < 4; ++e) {
            const float* wp = W_out + (size_t)(k0 + e) * V_;
            const float xv = he[e];
#pragma unroll
            for (int v = 0; v < 6; ++v) s[v] = fmaf(xv, wp[v], s[v]);
        }
    }
#pragma unroll
    for (int m = 1; m < 64; m <<= 1) {
#pragma unroll
        for (int v = 0; v < 6; ++v) s[v] += __shfl_xor(s[v], m, 64);
    }

    float lg[6];
#pragma unroll
    for (int v = 0; v < 6; ++v) lg[v] = s[v] + b_out[v];

    const float* ub = u + (size_t)b * V_;
    const float eps = 1e-10f;
    float aa[6];
#pragma unroll
    for (int v = 0; v < 6; ++v) {
        const float g = -logf(-logf(ub[v] + eps) + eps);
        aa[v] = lg[v] + g;  // TAU = 1
    }
    int tok = 0;
    float best = aa[0];
#pragma unroll
    for (int v = 1; v < 6; ++v)
        if (aa[v] > best) { best = aa[v]; tok = v; }

    if (lane == 0) {
        const float rco = rc[b];
#pragma unroll
        for (int v = 0; v < 6; ++v) out_logits[(size_t)b * 6 + v] = lg[v];
#pragma unroll
        for (int v = 0; v < 6; ++v)
            out_msg[(size_t)b * 36 + t * 6 + v] = (v == tok) ? rco : 0.0f;
        const float ntn = nt[b] + rco;
        nt[b] = ntn;
        out_nt[b] = ntn;
        rc[b] = (tok == 5) ? 0.0f : rco;
        tokidx[b] = tok;
    }
}

// ---------------------------------------------------------------------------
extern "C" void kernel_launch(void* const* d_in, const int* in_sizes, int n_in,
                              void* d_out, int out_size, void* d_ws, size_t ws_size,
                              hipStream_t stream)
{
    (void)in_sizes; (void)n_in; (void)out_size; (void)ws_size;
    const float* x       = (const float*)d_in[0];
    const float* u_noise = (const float*)d_in[1];
    const float* W_enc   = (const float*)d_in[2];
    const float* b_enc   = (const float*)d_in[3];
    const float* start_e = (const float*)d_in[4];
    const float* W_tok   = (const float*)d_in[5];
    const float* b_tok   = (const float*)d_in[6];
    const float* Wz      = (const float*)d_in[7];
    const float* bz      = (const float*)d_in[8];
    const float* Wr      = (const float*)d_in[9];
    const float* br      = (const float*)d_in[10];
    const float* Wh      = (const float*)d_in[11];
    const float* bh      = (const float*)d_in[12];
    const float* W_out   = (const float*)d_in[13];
    const float* b_out   = (const float*)d_in[14];

    float* out = (float*)d_out;
    float* out_msg = out;                                   // (B, T*V)
    float* out_logits = out + (size_t)B_ * T_ * V_;         // (T, B, V)
    float* out_nt = out_logits + (size_t)T_ * B_ * V_;      // (B,)

    // ---- workspace layout (~148.1 MB) ----
    char* wsb = (char*)d_ws;
    const size_t MB = 1024 * 1024;
    unsigned short* wzb_hi = (unsigned short*)(wsb + 0 * MB);    // 2MB each
    unsigned short* wzb_lo = (unsigned short*)(wsb + 2 * MB);
    unsigned short* wrb_hi = (unsigned short*)(wsb + 4 * MB);
    unsigned short* wrb_lo = (unsigned short*)(wsb + 6 * MB);
    unsigned short* whb_hi = (unsigned short*)(wsb + 8 * MB);
    unsigned short* whb_lo = (unsigned short*)(wsb + 10 * MB);
    unsigned short* we_hi  = (unsigned short*)(wsb + 12 * MB);   // 4MB
    unsigned short* we_lo  = (unsigned short*)(wsb + 16 * MB);   // 4MB
    unsigned short* x_hi   = (unsigned short*)(wsb + 20 * MB);   // 32MB
    unsigned short* x_lo   = (unsigned short*)(wsb + 52 * MB);   // 32MB
    float*  zbuf  = (float*)(wsb + 20 * MB);                     // alias x_hi
    unsigned short* rh_hi  = (unsigned short*)(wsb + 52 * MB);   // alias x_lo
    unsigned short* rh_lo  = (unsigned short*)(wsb + 68 * MB);
    float*  hbuf  = (float*)(wsb + 84 * MB);                     // 32MB
    unsigned short* h_hi   = (unsigned short*)(wsb + 116 * MB);  // 16MB
    unsigned short* h_lo   = (unsigned short*)(wsb + 132 * MB);  // 16MB
    float* Pz = (float*)(wsb + 148 * MB);                        // 7x1024 each
    float* Pr = Pz + 7 * 1024;
    float* Ph = Pr + 7 * 1024;
    int* tokidx = (int*)(Ph + 7 * 1024);
    float* rcb = (float*)(tokidx + B_);
    float* ntb = rcb + B_;

    // ---- one-time conversions / tables ----
    conv_wb<<<512, 256, 0, stream>>>(Wz, wzb_hi, wzb_lo);
    conv_wb<<<512, 256, 0, stream>>>(Wr, wrb_hi, wrb_lo);
    conv_wb<<<512, 256, 0, stream>>>(Wh, whb_hi, whb_lo);
    conv_w<<<1024, 256, 0, stream>>>(W_enc, we_hi, we_lo);
    conv_x<<<8192, 256, 0, stream>>>(x, x_hi, x_lo);
    prep_tables<<<dim3(4, 3), 256, 0, stream>>>(Wz, Wr, Wh, bz, br, bh,
                                                W_tok, b_tok, start_e, Pz, Pr, Ph);
    init_misc<<<32, 256, 0, stream>>>(tokidx, rcb, ntb);

    // ---- encoder: h0 = x @ W_enc + b_enc (K=2048) ----
    gemm_bt<<<dim3(8, 64), 256, 0, stream>>>(
        x_hi, x_lo, we_hi, we_lo, nullptr, nullptr,
        b_enc, nullptr, nullptr,
        nullptr, hbuf, nullptr, h_hi, h_lo, 256, 0);

    for (int t = 0; t < T_; ++t) {
        // z = sigmoid(h@Wz_bot + Pz[tok]); rh = sigmoid(h@Wr_bot + Pr[tok]) * h
        gemm_bt<<<dim3(16, 64), 256, 0, stream>>>(
            h_hi, h_lo, wzb_hi, wzb_lo, wrb_hi, wrb_lo,
            Pz, Pr, tokidx,
            nullptr, hbuf, zbuf, rh_hi, rh_lo, 128, 1);
        // h = (1-z)h + z*tanh(rh@Wh_bot + Ph[tok])
        gemm_bt<<<dim3(8, 64), 256, 0, stream>>>(
            rh_hi, rh_lo, whb_hi, whb_lo, nullptr, nullptr,
            Ph, nullptr, tokidx,
            zbuf, hbuf, nullptr, h_hi, h_lo, 128, 2);
        // logits / gumbel argmax / outputs / tokidx
        step_tok<<<B_ / 4, 256, 0, stream>>>(
            hbuf, W_out, b_out, u_noise + (size_t)t * B_ * V_,
            rcb, ntb, tokidx, out_msg,
            out_logits + (size_t)t * B_ * V_, out_nt, t);
    }
}